// Round 2
// baseline (6495.527 us; speedup 1.0000x reference)
//
#include <hip/hip_runtime.h>
#include <cfloat>
#include <math.h>

#define N 512
typedef unsigned long long u64_t;

__device__ __forceinline__ u64_t map_f64(double x) {
    u64_t b = (u64_t)__double_as_longlong(x);
    return b ^ ((b >> 63) ? 0xFFFFFFFFFFFFFFFFull : 0x8000000000000000ull);
}
__device__ __forceinline__ double unmap_f64(u64_t b) {
    b ^= ((b >> 63) ? 0x8000000000000000ull : 0xFFFFFFFFFFFFFFFFull);
    return __longlong_as_double((long long)b);
}

// wave64 u64 min-reduce via DPP (VALU pipe, ~90cy). Valid result in lane 63.
// row_shr:1/2/4/8 reduce within 16-lane rows; row_bcast:15/31 merge rows.
// bound_ctrl=false + old=own value => lanes w/o source keep own (min identity).
__device__ __forceinline__ u64_t wave_min_key(u64_t key) {
    unsigned hi = (unsigned)(key >> 32), lo = (unsigned)key;
#define MIN_STAGE(CTRL)                                                        \
    {                                                                          \
        unsigned oh = (unsigned)__builtin_amdgcn_update_dpp((int)hi, (int)hi,  \
                                                            CTRL, 0xF, 0xF, false); \
        unsigned ol = (unsigned)__builtin_amdgcn_update_dpp((int)lo, (int)lo,  \
                                                            CTRL, 0xF, 0xF, false); \
        const u64_t o = ((u64_t)oh << 32) | ol;                                \
        const u64_t c = ((u64_t)hi << 32) | lo;                                \
        if (o < c) { hi = oh; lo = ol; }                                       \
    }
    MIN_STAGE(0x111) MIN_STAGE(0x112) MIN_STAGE(0x114) MIN_STAGE(0x118)
    MIN_STAGE(0x142) MIN_STAGE(0x143)
#undef MIN_STAGE
    return ((u64_t)hi << 32) | lo;
}

// 512 threads / 8 waves, thread t owns column t+1. Exact JV:
// column reduction + greedy tight match + TWO LAPJV ARR warm-start passes
// (canonical LAPJV runs ARR twice; pass-2 cap scoped to residual free rows),
// then Dijkstra with DPP wave-reduce + 8-way ds_min_u64 combine.
// key = [45b value | 9b col-1 | 10b p[col]] (truncation precedent: absmax 0).
// R1 lesson: inner loop is serial-LATENCY-bound (not VALU-issue-bound);
// global-L2 cost matrix lengthened the chain (+100cy/iter). Keep LDS pt+sqrt.
__global__ __launch_bounds__(512, 1) void tofu_solver(
    const float* __restrict__ dgm, const float* __restrict__ dgm_x,
    float* __restrict__ out)
{
#pragma clang fp contract(off)
    __shared__ double2 pt[N];
    __shared__ double  u_lds[N + 1];
    __shared__ int     p_lds[N + 1];
    __shared__ int     way_lds[N + 1];
    __shared__ int     claim[N + 1];
    __shared__ int     flist[4 * N + 32];
    __shared__ u64_t   dslot[3];        // Dijkstra combine slots (mod-3 rotation)
    __shared__ u64_t   aslot[2], bslot[2];  // ARR slots (parity)
    __shared__ double  v1x;
    __shared__ double  red8[8];
    __shared__ int     nfree_s;

    const int tid  = threadIdx.x;       // 0..511
    const int col  = tid + 1;           // 1..512
    const int lane = tid & 63;
    const int wid  = tid >> 6;
    const float2* dgm2  = (const float2*)dgm;
    const float2* dgmx2 = (const float2*)dgm_x;

    // ---- stage points; own column's target point in registers ----
    {
        const float2 p2 = dgm2[tid];
        pt[tid] = make_double2((double)p2.x, (double)p2.y);
    }
    const float2 q2 = dgmx2[tid];
    const double xb = (double)q2.x, xd = (double)q2.y;
    u_lds[col] = 0.0; p_lds[col] = 0; way_lds[col] = 0; claim[col] = 0x7fffffff;
    if (tid == 0) {
        u_lds[0] = 0.0; p_lds[0] = 0; way_lds[0] = 0; claim[0] = 0x7fffffff;
        dslot[0] = dslot[1] = dslot[2] = ~0ull;
        aslot[0] = aslot[1] = ~0ull; bslot[0] = bslot[1] = ~0ull;
    }
    __syncthreads();

    // ---- column reduction: argmin over squared dist (sqrt monotone => same v) ----
    double v_j; int amin;
    {
        double vsq = DBL_MAX; amin = 1;
        for (int i = 0; i < N; ++i) {
            const double2 rp = pt[i];                 // broadcast b128
            const double db = rp.x - xb, dd = rp.y - xd;
            const double sq = db * db + dd * dd;
            if (sq < vsq) { vsq = sq; amin = i + 1; }
        }
        v_j = sqrt(vsq);                              // exact: sqrt(min) == min(sqrt)
    }

    // ---- greedy tight matching: row r -> smallest col whose argmin is r ----
    atomicMin(&claim[amin], col);
    __syncthreads();
    if (claim[amin] == col) p_lds[col] = amin;        // tight: c=v[col], u=0
    __syncthreads();

    // ---- LAPJV augmenting row reduction: TWO passes (canonical), each capped ----
    // Pass invariants (both passes): processing free row i uses val_j = c(i,j)-v_j
    // (u[i] ignored/overwritten: classic ARR re-derives u[i] = 2nd-min, feasible
    // since val_j >= m2 for all j != j1 and v[j1] -= (u[i]-val) restores tightness;
    // v only decreases, so displaced rows keep feasibility with their stale u).
    for (int pass = 0; pass < 2; ++pass) {
        // build freelist of currently-unmatched rows + reset combine slots
        claim[col] = 0;
        __syncthreads();
        { const int r = p_lds[col]; if (r) claim[r] = 1; }
        __syncthreads();
        if (tid == 0) {
            int nf = 0;
            for (int r = 1; r <= N; ++r) if (!claim[r]) flist[nf++] = r;
            nfree_s = nf;
            aslot[0] = aslot[1] = ~0ull; bslot[0] = bslot[1] = ~0ull;  // 2 barriers since last read
        }
        __syncthreads();

        int head = 0, tail = nfree_s, q = 0;
        const int cap = 3 * tail + 16;
        int myp = p_lds[col];                          // register copy of p[col]
        for (int step = 0; step < cap && head < tail; ++step) {
            const int i = flist[head++];               // uniform broadcast
            const double2 rp = pt[i - 1];
            const double db = rp.x - xb, dd = rp.y - xd;
            const double val = sqrt(db * db + dd * dd) - v_j;   // exact f64
            const u64_t key = (map_f64(val) & ~0x7FFFFull)
                            | ((u64_t)(col - 1) << 10) | (u64_t)myp;
            u64_t kr = wave_min_key(key);
            if (lane == 63) atomicMin(&aslot[q], kr);
            __syncthreads();                           // barrier 1
            const u64_t k1 = aslot[q];
            const int j1    = (int)((k1 >> 10) & 511) + 1;
            const int k_old = (int)(k1 & 1023);
            if (col == j1) v1x = val;                  // exact v1 handoff
            kr = wave_min_key((col == j1) ? ~0ull : key);
            if (lane == 63) atomicMin(&bslot[q], kr);
            __syncthreads();                           // barrier 2
            const double m2t = unmap_f64(bslot[q] & ~0x7FFFFull);  // <= true 2nd-min
            const double v1e = v1x;
            const double ui  = fmax(m2t, v1e);         // feasible AND tight on j1
            if (col == j1) { v_j -= (ui - val); myp = i; }
            if (tid == 0) {
                u_lds[i] = ui;
                p_lds[j1] = i;
                if (k_old) flist[tail] = k_old;
                aslot[q ^ 1] = ~0ull; bslot[q ^ 1] = ~0ull;  // safe: 2 barriers since last read
            }
            if (k_old) ++tail;                         // uniform
            q ^= 1;
            __syncthreads();                           // barrier 3
        }
    }

    // ---- rebuild freelist from p for the Dijkstra phase ----
    claim[col] = 0;
    __syncthreads();
    { const int r = p_lds[col]; if (r) claim[r] = 1; }
    __syncthreads();
    if (tid == 0) {
        int nf = 0;
        for (int r = 1; r <= N; ++r) if (!claim[r]) flist[nf++] = r;
        nfree_s = nf;
    }
    __syncthreads();
    const int nfree = nfree_s;

    // ---- exact Dijkstra phase ----
    for (int kk = 0; kk < nfree; ++kk) {
        const int iroot = flist[kk];                   // ordered by prev end barrier
        const int pcol  = p_lds[col];                  // static during this Dijkstra
        if (tid == 0) p_lds[0] = iroot;                // only tid0 reads p[0] (augment)
        double minv = DBL_MAX, du = 0.0, du0 = 0.0;
        bool used = false;
        int juse = 0, i0 = iroot, par = 0;

        while (true) {
            // ---- A-phase ----
            if (col == juse) used = true;              // mark prev winner
            const double2 rp = pt[i0 - 1];             // broadcast b128
            const double u0 = u_lds[i0];               // untouched this Dijkstra
            u64_t key = ~0ull;
            if (!used) {
                const double db = rp.x - xb, dd = rp.y - xd;
                const double c = sqrt(db * db + dd * dd);
                const double cur = (c - u0) - v_j;
                if (cur < minv) { minv = cur; way_lds[col] = juse; }
                key = (map_f64(minv) & ~0x7FFFFull)
                    | ((u64_t)(col - 1) << 10) | (u64_t)pcol;
            }
            key = wave_min_key(key);
            if (lane == 63) atomicMin(&dslot[par], key);
            __syncthreads();
            // ---- B-phase ----
            const u64_t k = dslot[par];
            if (tid == 0) dslot[(par + 2) % 3] = ~0ull;  // last read 2 barriers ago
            const double delta = unmap_f64(k & ~0x7FFFFull);  // <= every free minv
            if (used) { v_j -= delta; du += delta; }
            else        minv -= delta;
            if (tid == 0) du0 += delta;
            juse = (int)((k >> 10) & 511) + 1;
            i0   = (int)(k & 1023);                    // p payload; 0 => free col
            if (i0 == 0) break;
            par = (par + 1) % 3;
        }

        // epilogue: flush duals (distinct rows => race-free), augment, clean slot
        if (used) u_lds[pcol] += du;
        if (tid == 0) {
            u_lds[iroot] += du0;
            dslot[par] = ~0ull;                        // the slot just consumed
            int j = juse;
            while (j) { const int jn = way_lds[j]; p_lds[j] = p_lds[jn]; j = jn; }
        }
        __syncthreads();
    }

    // ---- loss = 0.5 * sum_j ||dgm[p[j]-1] - dgm_x[j-1]||^2 (f32 diffs like ref) ----
    const int r = p_lds[col] - 1;
    const float2 a = dgm2[r];
    const float2 b = dgmx2[tid];
    const float fb = a.x - b.x;
    const float fd = a.y - b.y;
    double acc = (double)fb * (double)fb + (double)fd * (double)fd;
    #pragma unroll
    for (int m = 32; m >= 1; m >>= 1) acc += __shfl_xor(acc, m, 64);
    if (lane == 0) red8[wid] = acc;
    __syncthreads();
    if (tid == 0) {
        double s = 0.0;
        #pragma unroll
        for (int w = 0; w < 8; ++w) s += red8[w];
        out[0] = (float)(0.5 * s);
    }
}

extern "C" void kernel_launch(void* const* d_in, const int* in_sizes, int n_in,
                              void* d_out, int out_size, void* d_ws, size_t ws_size,
                              hipStream_t stream) {
    const float* dgm   = (const float*)d_in[0];
    const float* dgm_x = (const float*)d_in[1];
    float* out = (float*)d_out;
    tofu_solver<<<1, 512, 0, stream>>>(dgm, dgm_x, out);
}

// Round 3
// 6306.097 us; speedup vs baseline: 1.0300x; 1.0300x over previous
//
#include <hip/hip_runtime.h>
#include <cfloat>
#include <math.h>

#define N 512
typedef unsigned long long u64_t;

__device__ __forceinline__ u64_t map_f64(double x) {
    u64_t b = (u64_t)__double_as_longlong(x);
    return b ^ ((b >> 63) ? 0xFFFFFFFFFFFFFFFFull : 0x8000000000000000ull);
}
__device__ __forceinline__ double unmap_f64(u64_t b) {
    b ^= ((b >> 63) ? 0x8000000000000000ull : 0xFFFFFFFFFFFFFFFFull);
    return __longlong_as_double((long long)b);
}

// wave64 u64 min-reduce via DPP (VALU pipe). Valid result in lane 63.
__device__ __forceinline__ u64_t wave_min_key(u64_t key) {
    unsigned hi = (unsigned)(key >> 32), lo = (unsigned)key;
#define MIN_STAGE(CTRL)                                                        \
    {                                                                          \
        unsigned oh = (unsigned)__builtin_amdgcn_update_dpp((int)hi, (int)hi,  \
                                                            CTRL, 0xF, 0xF, false); \
        unsigned ol = (unsigned)__builtin_amdgcn_update_dpp((int)lo, (int)lo,  \
                                                            CTRL, 0xF, 0xF, false); \
        const u64_t o = ((u64_t)oh << 32) | ol;                                \
        const u64_t c = ((u64_t)hi << 32) | lo;                                \
        if (o < c) { hi = oh; lo = ol; }                                       \
    }
    MIN_STAGE(0x111) MIN_STAGE(0x112) MIN_STAGE(0x114) MIN_STAGE(0x118)
    MIN_STAGE(0x142) MIN_STAGE(0x143)
#undef MIN_STAGE
    return ((u64_t)hi << 32) | lo;
}

__device__ __forceinline__ u64_t min4_u64(const u64_t* s) {
    const u64_t a = s[0], b = s[1], c = s[2], d = s[3];
    const u64_t m0 = (a < b) ? a : b;
    const u64_t m1 = (c < d) ? c : d;
    return (m0 < m1) ? m0 : m1;
}

// 256 threads / 4 waves (1 wave/SIMD: no issue contention), thread t owns
// columns t+1 and t+257. Exact JV: column reduction + greedy tight match +
// ONE LAPJV ARR warm-start pass (R2: a second pass churns, +715us), then
// Dijkstra. Combine = thread-local min(2 keys) -> DPP wave-min -> plain
// ds_write to per-wave slot (parity dbuf; no atomicMin: 8-way same-address
// atomic serialization was part of the measured ~1200cy/barrier interval)
// -> barrier -> all threads min-tree the 4 slots. Min over distinct u64 keys
// is order-independent => bit-identical trajectory to the 8-wave version.
// key = [45b value | 9b col-1 | 10b p[col]] (truncation precedent: absmax 0).
// R1 lesson: loop is serial-LATENCY-bound; keep LDS pt + sqrt (L2 was worse).
__global__ __launch_bounds__(256, 1) void tofu_solver(
    const float* __restrict__ dgm, const float* __restrict__ dgm_x,
    float* __restrict__ out)
{
#pragma clang fp contract(off)
    __shared__ double2 pt[N];
    __shared__ double  u_lds[N + 1];
    __shared__ int     p_lds[N + 1];
    __shared__ int     way_lds[N + 1];
    __shared__ int     claim[N + 1];
    __shared__ int     flist[4 * N + 32];
    __shared__ u64_t   dslot[2][4];     // Dijkstra combine slots (parity)
    __shared__ u64_t   aslot[2][4], bslot[2][4];  // ARR slots (parity)
    __shared__ double  v1x;
    __shared__ double  red4[4];
    __shared__ int     nfree_s;

    const int tid  = threadIdx.x;       // 0..255
    const int col0 = tid + 1;           // 1..256
    const int col1 = tid + 257;         // 257..512
    const int lane = tid & 63;
    const int wid  = tid >> 6;          // 0..3
    const float2* dgm2  = (const float2*)dgm;
    const float2* dgmx2 = (const float2*)dgm_x;

    // ---- stage points; own columns' target points in registers ----
    {
        float2 p2 = dgm2[tid];
        pt[tid] = make_double2((double)p2.x, (double)p2.y);
        p2 = dgm2[tid + 256];
        pt[tid + 256] = make_double2((double)p2.x, (double)p2.y);
    }
    const float2 qa = dgmx2[tid];
    const float2 qb = dgmx2[tid + 256];
    const double xb0 = (double)qa.x, xd0 = (double)qa.y;
    const double xb1 = (double)qb.x, xd1 = (double)qb.y;
    u_lds[col0] = 0.0; p_lds[col0] = 0; way_lds[col0] = 0; claim[col0] = 0x7fffffff;
    u_lds[col1] = 0.0; p_lds[col1] = 0; way_lds[col1] = 0; claim[col1] = 0x7fffffff;
    if (tid == 0) {
        u_lds[0] = 0.0; p_lds[0] = 0; way_lds[0] = 0; claim[0] = 0x7fffffff;
        // slots need no init: plain-overwritten by every wave before first read
    }
    __syncthreads();

    // ---- column reduction: argmin over squared dist (sqrt monotone => same v) ----
    double v_j0, v_j1; int amin0, amin1;
    {
        double vsq0 = DBL_MAX, vsq1 = DBL_MAX; amin0 = 1; amin1 = 1;
        for (int i = 0; i < N; ++i) {
            const double2 rp = pt[i];                 // broadcast b128
            const double db0 = rp.x - xb0, dd0 = rp.y - xd0;
            const double db1 = rp.x - xb1, dd1 = rp.y - xd1;
            const double sq0 = db0 * db0 + dd0 * dd0;
            const double sq1 = db1 * db1 + dd1 * dd1;
            if (sq0 < vsq0) { vsq0 = sq0; amin0 = i + 1; }
            if (sq1 < vsq1) { vsq1 = sq1; amin1 = i + 1; }
        }
        v_j0 = sqrt(vsq0);                            // exact: sqrt(min) == min(sqrt)
        v_j1 = sqrt(vsq1);
    }

    // ---- greedy tight matching: row r -> smallest col whose argmin is r ----
    atomicMin(&claim[amin0], col0);
    atomicMin(&claim[amin1], col1);
    __syncthreads();
    if (claim[amin0] == col0) p_lds[col0] = amin0;    // tight: c=v[col], u=0
    if (claim[amin1] == col1) p_lds[col1] = amin1;
    __syncthreads();
    // freelist of unmatched rows
    claim[col0] = 0; claim[col1] = 0;
    __syncthreads();
    { const int r = p_lds[col0]; if (r) claim[r] = 1; }
    { const int r = p_lds[col1]; if (r) claim[r] = 1; }
    __syncthreads();
    if (tid == 0) {
        int nf = 0;
        for (int r = 1; r <= N; ++r) if (!claim[r]) flist[nf++] = r;
        nfree_s = nf;
    }
    __syncthreads();

    // ---- LAPJV augmenting row reduction (one pass, exactness-preserving, capped) ----
    {
        int head = 0, tail = nfree_s, q = 0;
        const int cap = 3 * tail + 16;
        int myp0 = p_lds[col0], myp1 = p_lds[col1];    // register copies of p[col]
        for (int step = 0; step < cap && head < tail; ++step) {
            const int i = flist[head++];               // uniform broadcast
            const double2 rp = pt[i - 1];
            const double db0 = rp.x - xb0, dd0 = rp.y - xd0;
            const double db1 = rp.x - xb1, dd1 = rp.y - xd1;
            const double val0 = sqrt(db0 * db0 + dd0 * dd0) - v_j0;   // exact f64
            const double val1 = sqrt(db1 * db1 + dd1 * dd1) - v_j1;
            const u64_t key0 = (map_f64(val0) & ~0x7FFFFull)
                             | ((u64_t)(col0 - 1) << 10) | (u64_t)myp0;
            const u64_t key1 = (map_f64(val1) & ~0x7FFFFull)
                             | ((u64_t)(col1 - 1) << 10) | (u64_t)myp1;
            u64_t kr = wave_min_key((key0 < key1) ? key0 : key1);
            if (lane == 63) aslot[q][wid] = kr;
            __syncthreads();                           // barrier 1
            const u64_t k1 = min4_u64(aslot[q]);
            const int j1    = (int)((k1 >> 10) & 511) + 1;
            const int k_old = (int)(k1 & 1023);
            if (col0 == j1) v1x = val0;                // exact v1 handoff
            if (col1 == j1) v1x = val1;
            const u64_t e0 = (col0 == j1) ? ~0ull : key0;
            const u64_t e1 = (col1 == j1) ? ~0ull : key1;
            kr = wave_min_key((e0 < e1) ? e0 : e1);
            if (lane == 63) bslot[q][wid] = kr;
            __syncthreads();                           // barrier 2
            const double m2t = unmap_f64(min4_u64(bslot[q]) & ~0x7FFFFull);  // <= true 2nd-min
            const double v1e = v1x;
            const double ui  = fmax(m2t, v1e);         // feasible AND tight on j1
            if (col0 == j1) { v_j0 -= (ui - val0); myp0 = i; }
            if (col1 == j1) { v_j1 -= (ui - val1); myp1 = i; }
            if (tid == 0) {
                u_lds[i] = ui;
                p_lds[j1] = i;
                if (k_old) flist[tail] = k_old;
            }
            if (k_old) ++tail;                         // uniform
            q ^= 1;
            __syncthreads();                           // barrier 3
        }
    }

    // ---- rebuild freelist from p ----
    claim[col0] = 0; claim[col1] = 0;
    __syncthreads();
    { const int r = p_lds[col0]; if (r) claim[r] = 1; }
    { const int r = p_lds[col1]; if (r) claim[r] = 1; }
    __syncthreads();
    if (tid == 0) {
        int nf = 0;
        for (int r = 1; r <= N; ++r) if (!claim[r]) flist[nf++] = r;
        nfree_s = nf;
    }
    __syncthreads();
    const int nfree = nfree_s;

    // ---- exact Dijkstra phase ----
    for (int kk = 0; kk < nfree; ++kk) {
        const int iroot = flist[kk];                   // ordered by prev end barrier
        const int pcol0 = p_lds[col0];                 // static during this Dijkstra
        const int pcol1 = p_lds[col1];
        if (tid == 0) p_lds[0] = iroot;                // only tid0 reads p[0] (augment)
        double minv0 = DBL_MAX, minv1 = DBL_MAX;
        double duA = 0.0, duB = 0.0, du0 = 0.0;
        bool used0 = false, used1 = false;
        int juse = 0, i0 = iroot, par = 0;

        while (true) {
            // ---- A-phase ----
            if (col0 == juse) used0 = true;            // mark prev winner
            if (col1 == juse) used1 = true;
            const double2 rp = pt[i0 - 1];             // broadcast b128
            const double u0 = u_lds[i0];               // untouched this Dijkstra
            u64_t key = ~0ull;
            if (!used0) {
                const double db = rp.x - xb0, dd = rp.y - xd0;
                const double c = sqrt(db * db + dd * dd);
                const double cur = (c - u0) - v_j0;
                if (cur < minv0) { minv0 = cur; way_lds[col0] = juse; }
                key = (map_f64(minv0) & ~0x7FFFFull)
                    | ((u64_t)(col0 - 1) << 10) | (u64_t)pcol0;
            }
            if (!used1) {
                const double db = rp.x - xb1, dd = rp.y - xd1;
                const double c = sqrt(db * db + dd * dd);
                const double cur = (c - u0) - v_j1;
                if (cur < minv1) { minv1 = cur; way_lds[col1] = juse; }
                const u64_t k1 = (map_f64(minv1) & ~0x7FFFFull)
                               | ((u64_t)(col1 - 1) << 10) | (u64_t)pcol1;
                if (k1 < key) key = k1;
            }
            key = wave_min_key(key);
            if (lane == 63) dslot[par][wid] = key;
            __syncthreads();
            // ---- B-phase ----
            const u64_t k = min4_u64(dslot[par]);
            const double delta = unmap_f64(k & ~0x7FFFFull);  // <= every free minv
            if (used0) { v_j0 -= delta; duA += delta; } else minv0 -= delta;
            if (used1) { v_j1 -= delta; duB += delta; } else minv1 -= delta;
            if (tid == 0) du0 += delta;
            juse = (int)((k >> 10) & 511) + 1;
            i0   = (int)(k & 1023);                    // p payload; 0 => free col
            if (i0 == 0) break;
            par ^= 1;
        }

        // epilogue: flush duals (distinct rows => race-free), augment
        if (used0) u_lds[pcol0] += duA;
        if (used1) u_lds[pcol1] += duB;
        if (tid == 0) {
            u_lds[iroot] += du0;
            int j = juse;
            while (j) { const int jn = way_lds[j]; p_lds[j] = p_lds[jn]; j = jn; }
        }
        __syncthreads();
    }

    // ---- loss = 0.5 * sum_j ||dgm[p[j]-1] - dgm_x[j-1]||^2 (f32 diffs like ref) ----
    const int r0 = p_lds[col0] - 1;
    const int r1 = p_lds[col1] - 1;
    const float2 a0 = dgm2[r0];
    const float2 b0 = dgmx2[tid];
    const float2 a1 = dgm2[r1];
    const float2 b1 = dgmx2[tid + 256];
    const float fb0 = a0.x - b0.x, fd0 = a0.y - b0.y;
    const float fb1 = a1.x - b1.x, fd1 = a1.y - b1.y;
    double acc = (double)fb0 * (double)fb0 + (double)fd0 * (double)fd0
               + (double)fb1 * (double)fb1 + (double)fd1 * (double)fd1;
    #pragma unroll
    for (int m = 32; m >= 1; m >>= 1) acc += __shfl_xor(acc, m, 64);
    if (lane == 0) red4[wid] = acc;
    __syncthreads();
    if (tid == 0) {
        out[0] = (float)(0.5 * (red4[0] + red4[1] + red4[2] + red4[3]));
    }
}

extern "C" void kernel_launch(void* const* d_in, const int* in_sizes, int n_in,
                              void* d_out, int out_size, void* d_ws, size_t ws_size,
                              hipStream_t stream) {
    const float* dgm   = (const float*)d_in[0];
    const float* dgm_x = (const float*)d_in[1];
    float* out = (float*)d_out;
    tofu_solver<<<1, 256, 0, stream>>>(dgm, dgm_x, out);
}

// Round 4
// 5643.481 us; speedup vs baseline: 1.1510x; 1.1174x over previous
//
#include <hip/hip_runtime.h>
#include <cfloat>
#include <math.h>

#define N 512
typedef unsigned long long u64_t;

__device__ __forceinline__ u64_t map_f64(double x) {
    u64_t b = (u64_t)__double_as_longlong(x);
    return b ^ ((b >> 63) ? 0xFFFFFFFFFFFFFFFFull : 0x8000000000000000ull);
}
__device__ __forceinline__ double unmap_f64(u64_t b) {
    b ^= ((b >> 63) ? 0x8000000000000000ull : 0xFFFFFFFFFFFFFFFFull);
    return __longlong_as_double((long long)b);
}

// wave64 u64 min-reduce via DPP (VALU pipe). Valid result in lane 63.
// row_shr:1/2/4/8 reduce within 16-lane rows; row_bcast:15/31 merge rows.
// bound_ctrl=false + old=own value => lanes w/o source keep own (min identity).
__device__ __forceinline__ u64_t wave_min_key(u64_t key) {
    unsigned hi = (unsigned)(key >> 32), lo = (unsigned)key;
#define MIN_STAGE(CTRL)                                                        \
    {                                                                          \
        unsigned oh = (unsigned)__builtin_amdgcn_update_dpp((int)hi, (int)hi,  \
                                                            CTRL, 0xF, 0xF, false); \
        unsigned ol = (unsigned)__builtin_amdgcn_update_dpp((int)lo, (int)lo,  \
                                                            CTRL, 0xF, 0xF, false); \
        const u64_t o = ((u64_t)oh << 32) | ol;                                \
        const u64_t c = ((u64_t)hi << 32) | lo;                                \
        if (o < c) { hi = oh; lo = ol; }                                       \
    }
    MIN_STAGE(0x111) MIN_STAGE(0x112) MIN_STAGE(0x114) MIN_STAGE(0x118)
    MIN_STAGE(0x142) MIN_STAGE(0x143)
#undef MIN_STAGE
    return ((u64_t)hi << 32) | lo;
}

// 512 threads / 8 waves, thread t owns column t+1. Exact JV:
// column reduction + greedy tight match + LAPJV ARR warm start, then
// Dijkstra with DPP wave-reduce + 8-way atomicMin combine.
// key = [45b value | 9b col-1 | 10b p[col]] (truncation precedent: absmax 0).
// R1-R3 lessons: loop is serial-LATENCY-bound on the per-iteration chain
// (slot read -> pt/u read -> sqrt -> DPP -> barrier ~= 1150cy measured);
// wave count, atomics, L2-cost-matrix all neutral-to-worse. R4 attacks the
// chain terms directly in the Dijkstra loop:
//  (1) squared-distance filter: skip f64 sqrt for lanes provably unable to
//      improve (c < T  <=>  s < T^2; 1e-12 abs slack >> 1e-15 fl error, so
//      skipped lanes are exactly the no-update lanes -> updates unchanged);
//  (2) absolute dist labels (no minv-=delta): key ordering identical (all
//      free cols shared the same cumulative decrement); duals settled in
//      epilogue via D_end - D_win. fl-noise ~1e-16 << tolerated 2^-33 trunc;
//  (3) wave-min caching: stable keys => waves with no update/transition skip
//      pack+DPP entirely; lane63 re-posts cached wave-min.
__global__ __launch_bounds__(512, 1) void tofu_solver(
    const float* __restrict__ dgm, const float* __restrict__ dgm_x,
    float* __restrict__ out)
{
#pragma clang fp contract(off)
    __shared__ double2 pt[N];
    __shared__ double  u_lds[N + 1];
    __shared__ int     p_lds[N + 1];
    __shared__ int     way_lds[N + 1];
    __shared__ int     claim[N + 1];
    __shared__ int     flist[4 * N + 32];
    __shared__ u64_t   dslot[3];        // Dijkstra combine slots (mod-3 rotation)
    __shared__ u64_t   aslot[2], bslot[2];  // ARR slots (parity)
    __shared__ double  v1x;
    __shared__ double  red8[8];
    __shared__ int     nfree_s;

    const int tid  = threadIdx.x;       // 0..511
    const int col  = tid + 1;           // 1..512
    const int lane = tid & 63;
    const int wid  = tid >> 6;
    const float2* dgm2  = (const float2*)dgm;
    const float2* dgmx2 = (const float2*)dgm_x;

    // ---- stage points; own column's target point in registers ----
    {
        const float2 p2 = dgm2[tid];
        pt[tid] = make_double2((double)p2.x, (double)p2.y);
    }
    const float2 q2 = dgmx2[tid];
    const double xb = (double)q2.x, xd = (double)q2.y;
    u_lds[col] = 0.0; p_lds[col] = 0; way_lds[col] = 0; claim[col] = 0x7fffffff;
    if (tid == 0) {
        u_lds[0] = 0.0; p_lds[0] = 0; way_lds[0] = 0; claim[0] = 0x7fffffff;
        dslot[0] = dslot[1] = dslot[2] = ~0ull;
        aslot[0] = aslot[1] = ~0ull; bslot[0] = bslot[1] = ~0ull;
    }
    __syncthreads();

    // ---- column reduction: argmin over squared dist (sqrt monotone => same v) ----
    double v_j; int amin;
    {
        double vsq = DBL_MAX; amin = 1;
        for (int i = 0; i < N; ++i) {
            const double2 rp = pt[i];                 // broadcast b128
            const double db = rp.x - xb, dd = rp.y - xd;
            const double sq = db * db + dd * dd;
            if (sq < vsq) { vsq = sq; amin = i + 1; }
        }
        v_j = sqrt(vsq);                              // exact: sqrt(min) == min(sqrt)
    }

    // ---- greedy tight matching: row r -> smallest col whose argmin is r ----
    atomicMin(&claim[amin], col);
    __syncthreads();
    if (claim[amin] == col) p_lds[col] = amin;        // tight: c=v[col], u=0
    __syncthreads();
    // freelist of unmatched rows
    claim[col] = 0;
    __syncthreads();
    { const int r = p_lds[col]; if (r) claim[r] = 1; }
    __syncthreads();
    if (tid == 0) {
        int nf = 0;
        for (int r = 1; r <= N; ++r) if (!claim[r]) flist[nf++] = r;
        nfree_s = nf;
    }
    __syncthreads();

    // ---- LAPJV augmenting row reduction (exactness-preserving, capped) ----
    {
        int head = 0, tail = nfree_s, q = 0;
        const int cap = 3 * tail + 16;
        int myp = p_lds[col];                          // register copy of p[col]
        for (int step = 0; step < cap && head < tail; ++step) {
            const int i = flist[head++];               // uniform broadcast
            const double2 rp = pt[i - 1];
            const double db = rp.x - xb, dd = rp.y - xd;
            const double val = sqrt(db * db + dd * dd) - v_j;   // exact f64
            const u64_t key = (map_f64(val) & ~0x7FFFFull)
                            | ((u64_t)(col - 1) << 10) | (u64_t)myp;
            u64_t kr = wave_min_key(key);
            if (lane == 63) atomicMin(&aslot[q], kr);
            __syncthreads();                           // barrier 1
            const u64_t k1 = aslot[q];
            const int j1    = (int)((k1 >> 10) & 511) + 1;
            const int k_old = (int)(k1 & 1023);
            if (col == j1) v1x = val;                  // exact v1 handoff
            kr = wave_min_key((col == j1) ? ~0ull : key);
            if (lane == 63) atomicMin(&bslot[q], kr);
            __syncthreads();                           // barrier 2
            const double m2t = unmap_f64(bslot[q] & ~0x7FFFFull);  // <= true 2nd-min
            const double v1e = v1x;
            const double ui  = fmax(m2t, v1e);         // feasible AND tight on j1
            if (col == j1) { v_j -= (ui - val); myp = i; }
            if (tid == 0) {
                u_lds[i] = ui;
                p_lds[j1] = i;
                if (k_old) flist[tail] = k_old;
                aslot[q ^ 1] = ~0ull; bslot[q ^ 1] = ~0ull;  // safe: 2 barriers since last read
            }
            if (k_old) ++tail;                         // uniform
            q ^= 1;
            __syncthreads();                           // barrier 3
        }
    }

    // ---- rebuild freelist from p ----
    claim[col] = 0;
    __syncthreads();
    { const int r = p_lds[col]; if (r) claim[r] = 1; }
    __syncthreads();
    if (tid == 0) {
        int nf = 0;
        for (int r = 1; r <= N; ++r) if (!claim[r]) flist[nf++] = r;
        nfree_s = nf;
    }
    __syncthreads();
    const int nfree = nfree_s;

    // ---- exact Dijkstra phase (absolute labels + sqrt filter + wave-min cache) ----
    for (int kk = 0; kk < nfree; ++kk) {
        const int iroot = flist[kk];                   // ordered by prev end barrier
        const int pcol  = p_lds[col];                  // static during this Dijkstra
        if (tid == 0) p_lds[0] = iroot;                // only tid0 reads p[0] (augment)
        double minv = DBL_MAX;                         // ABSOLUTE dist label (stable)
        double D = 0.0, Dwin = 0.0;                    // uniform frontier dist / win dist
        bool used = false;
        int juse = 0, i0 = iroot, par = 0;
        u64_t key  = ~0ull;                            // cached own key
        u64_t wmin = ~0ull;                            // lane63's cached wave-min

        while (true) {
            // ---- A-phase ----
            bool trans = false;
            if (col == juse) {                         // prev winner: mark used
                used = true; Dwin = D; trans = true; key = ~0ull;
            }
            const double2 rp = pt[i0 - 1];             // broadcast b128
            const double u0 = u_lds[i0];               // untouched this Dijkstra
            bool upd = false;
            if (!used) {
                const double db = rp.x - xb, dd = rp.y - xd;
                const double s = db * db + dd * dd;
                // cand < minv  <=>  c < ((minv - D) + u0) + v_j  (exact algebra);
                // conservative filter with 1e-12 abs slack (>> fl error) so only
                // provably-no-update lanes skip the sqrt.
                const double T  = ((minv - D) + u0) + v_j;
                const double Tp = T + 1e-12;
                if (Tp > 0.0 && s < Tp * Tp) {
                    const double c = sqrt(s);          // exact f64, same expr as before
                    const double cand = D + ((c - u0) - v_j);
                    if (cand < minv) {
                        minv = cand; way_lds[col] = juse; upd = true;
                        key = (map_f64(minv) & ~0x7FFFFull)
                            | ((u64_t)(col - 1) << 10) | (u64_t)pcol;
                    }
                }
            }
            if (__any((int)(upd || trans))) {          // wave-uniform: keys changed?
                wmin = wave_min_key(key);
            }
            if (lane == 63) atomicMin(&dslot[par], wmin);
            __syncthreads();
            // ---- B-phase ----
            const u64_t k = dslot[par];
            if (tid == 0) dslot[(par + 2) % 3] = ~0ull;  // last read 2 barriers ago
            D = unmap_f64(k & ~0x7FFFFull);            // winner's (truncated) abs dist
            juse = (int)((k >> 10) & 511) + 1;
            i0   = (int)(k & 1023);                    // p payload; 0 => free col
            if (i0 == 0) break;
            par = (par + 1) % 3;
        }

        // epilogue: settle duals (distinct rows => race-free), augment, clean slot
        if (used) {
            const double du = D - Dwin;                // == sum of deltas while used
            u_lds[pcol] += du;
            v_j -= du;
        }
        if (tid == 0) {
            u_lds[iroot] += D;                         // == sum of all deltas (D_end)
            dslot[par] = ~0ull;                        // the slot just consumed
            int j = juse;
            while (j) { const int jn = way_lds[j]; p_lds[j] = p_lds[jn]; j = jn; }
        }
        __syncthreads();
    }

    // ---- loss = 0.5 * sum_j ||dgm[p[j]-1] - dgm_x[j-1]||^2 (f32 diffs like ref) ----
    const int r = p_lds[col] - 1;
    const float2 a = dgm2[r];
    const float2 b = dgmx2[tid];
    const float fb = a.x - b.x;
    const float fd = a.y - b.y;
    double acc = (double)fb * (double)fb + (double)fd * (double)fd;
    #pragma unroll
    for (int m = 32; m >= 1; m >>= 1) acc += __shfl_xor(acc, m, 64);
    if (lane == 0) red8[wid] = acc;
    __syncthreads();
    if (tid == 0) {
        double s = 0.0;
        #pragma unroll
        for (int w = 0; w < 8; ++w) s += red8[w];
        out[0] = (float)(0.5 * s);
    }
}

extern "C" void kernel_launch(void* const* d_in, const int* in_sizes, int n_in,
                              void* d_out, int out_size, void* d_ws, size_t ws_size,
                              hipStream_t stream) {
    const float* dgm   = (const float*)d_in[0];
    const float* dgm_x = (const float*)d_in[1];
    float* out = (float*)d_out;
    tofu_solver<<<1, 512, 0, stream>>>(dgm, dgm_x, out);
}